// Round 9
// baseline (324.693 us; speedup 1.0000x reference)
//
#include <hip/hip_runtime.h>
#include <hip/hip_bf16.h>
#include <math.h>

// Swin block, MI355X round 15: R8 base (fused frozen) + mlp restructured for
// latency hiding: 32 rows/block, 384 thr (6 waves), LDS 25.1KB -> 5 blocks/CU
// (30 waves, was 3 blocks/18 waves), grid 6272. Evidence: R8's fc2 instruction
// cut was null for mlp while occupancy sat at 25% -> mlp is phase/latency-
// bound, not issue-bound. Work split stays balanced (fc1 24/6, fc2 6/6 tiles).

typedef __attribute__((ext_vector_type(8))) short bfrag8;   // 8 bf16 = 4 VGPRs
typedef __attribute__((ext_vector_type(4))) float f32x4;
typedef __attribute__((ext_vector_type(2))) unsigned int u32x2;

#define LOG2E 1.4426950408889634f

__device__ __forceinline__ float bf2f(unsigned short u){
  union { unsigned int i; float f; } c; c.i = ((unsigned int)u) << 16; return c.f;
}
__device__ __forceinline__ unsigned short f2bf(float f){
  __hip_bfloat16 h = __float2bfloat16(f);
  union { __hip_bfloat16 h; unsigned short u; } c; c.h = h; return c.u;
}
__device__ __forceinline__ u32x2 pack4(float a0, float a1, float a2, float a3){
  u32x2 r;
  r.x = (unsigned int)f2bf(a0) | ((unsigned int)f2bf(a1) << 16);
  r.y = (unsigned int)f2bf(a2) | ((unsigned int)f2bf(a3) << 16);
  return r;
}
// gelu(x) ~ x * sigmoid(1.5957691(x + 0.044715 x^3)), exp2-folded:
// x / (1 + exp2(x*(c1 + c2*x^2))), c1 = -1.5957691*log2e, c2 = c1*0.044715
__device__ __forceinline__ float gelu_f(float x){
  const float c1 = -2.302208198f, c2 = -0.1029432397f;
  float x2 = x * x;
  float t  = __builtin_fmaf(x2, c2, c1);
  float u  = exp2f(x * t);
  return x * __builtin_amdgcn_rcpf(1.f + u);
}

// 32-ush rows: granule xor (4 qd classes distinct); XOR bits 3-4 only ->
// 4-aligned groups stay contiguous (b64-safe).
__device__ __forceinline__ int swz32(int r, int c){
  return r * 32 + (c ^ (((r ^ (r >> 2)) & 3) << 3));
}
// 64-ush rows: granule xor bits 3-5; 4-aligned groups stay contiguous.
__device__ __forceinline__ int swz64(int r, int c){
  return r * 64 + (c ^ (((r ^ (r >> 3)) & 7) << 3));
}
// fp32 proj-output buffer (stride 96 floats): xor bits 2-4 by row; 4-float
// groups stay contiguous (f32x4-safe).
__device__ __forceinline__ int fswz(int r, int c){
  return r * 96 + (c ^ ((r & 7) << 2));
}

// window-order row r (win*49+n) -> image row (b*12544 + h*112 + w), shift +3.
__device__ __forceinline__ int win_to_img(int r){
  int win = r / 49, n = r - win * 49;
  int b  = win >> 8, wi = win & 255;
  int wh = wi >> 4,  ww = wi & 15;
  int i  = n / 7,    j  = n - i * 7;
  int hs = wh * 7 + i + 3; if (hs >= 112) hs -= 112;
  int ws = ww * 7 + j + 3; if (ws >= 112) ws -= 112;
  return b * 12544 + hs * 112 + ws;
}

// ---- weight conversions + scaled qkv bias in one kernel ---------------------
__global__ __launch_bounds__(256) void cvt_all_kernel(
    const float* __restrict__ s1, unsigned short* __restrict__ d1,   // 36864
    const float* __restrict__ s2, unsigned short* __restrict__ d2,   // 36864
    const float* __restrict__ s3, unsigned short* __restrict__ d3,   // 27648
    const float* __restrict__ s4, unsigned short* __restrict__ d4,   // 9216
    const float* __restrict__ bq, float* __restrict__ bqs)           // 288
{
  const float QS = 0.17677669529663687f * 1.4426950408889634f;
  int i = blockIdx.x * 256 + threadIdx.x;
  if      (i < 36864)  d1[i]          = f2bf(s1[i]);
  else if (i < 73728)  d2[i - 36864]  = f2bf(s2[i - 36864]);
  else if (i < 101376){
    int j = i - 73728;
    float v = s3[j];
    if (j < 9216) v *= QS;          // q rows: col < 96
    d3[j] = f2bf(v);
  }
  else if (i < 110592) d4[i - 101376] = f2bf(s4[i - 101376]);
  else if (i < 110880){
    int j = i - 110592;
    float v = bq[j];
    if (j < 96) v *= QS;
    bqs[j] = v;
  }
}

// ---- rel-bias + shift-mask table, 4 window classes, MFMA-fragment layout ----
// cbt[cls][h][mt][nt][qd][ln][r] fp32 * log2e; n>=49 -> -1e4, invalid m -> 0.
// cls: 0 interior, 1 ww=15, 2 wh=15, 3 corner (only 4 distinct Swin masks).
__global__ __launch_bounds__(256) void cb_kernel(
    const float* __restrict__ relt, const float* __restrict__ mask,
    float* __restrict__ cbt)
{
  int idx = blockIdx.x * 256 + threadIdx.x;      // 4*3*4096 = 49152 total
  int ch = idx >> 12;
  int cls = ch / 3, h = ch - cls * 3;
  int w = (cls == 0) ? 0 : (cls == 1) ? 15 : (cls == 2) ? 240 : 255;
  int rem = idx & 4095;
  int mt = rem >> 10, nt = (rem >> 8) & 3, qd = (rem >> 6) & 3;
  int ln = (rem >> 2) & 15, r = rem & 3;
  int m = mt * 16 + qd * 4 + r, n = nt * 16 + ln;
  float v;
  if (m < 49 && n < 49){
    int i1 = m / 7, j1 = m - i1 * 7;
    int i2 = n / 7, j2 = n - i2 * 7;
    int ridx = (i1 - i2 + 6) * 13 + (j1 - j2 + 6);
    v = (relt[ridx * 3 + h] + mask[w * 2401 + m * 49 + n]) * LOG2E;
  } else if (n >= 49) v = -10000.0f;
  else v = 0.0f;
  cbt[idx] = v;
}

// ---- fused per-window kernel: LN1 + qkv + attention + proj ------------------
// LDS 37.9KB: As[0,6656) -> vt/Os[0,6144) overlay; q/k/Ps per head at
// [6656+h*4096); Xf (fp32 64x96) overlays q/k/Ps at [6656,18944) in phase 4.
__global__ __launch_bounds__(256, 4) void fused_win_kernel(
    const float* __restrict__ x,
    const float* __restrict__ g1, const float* __restrict__ b1n,
    const unsigned short* __restrict__ wqkv, const float* __restrict__ bqs,
    const float* __restrict__ cbt,
    const unsigned short* __restrict__ wproj, const float* __restrict__ bproj,
    unsigned short* __restrict__ x2)
{
  __shared__ unsigned short L[18944];   // 37888 B

  int win = blockIdx.x, tid = threadIdx.x;

  // ---- phase 0: stage + LN1 -> As @ [0, 6656), b128 writes ------------------
  {
    int r = tid >> 2, part = tid & 3;
    if (r < 49){
      int gr = win_to_img(win * 49 + r);
      const float* rowp = x + (size_t)gr * 96 + part * 24;
      float v[24]; float s = 0.f, q = 0.f;
      #pragma unroll
      for (int c = 0; c < 24; c++){ v[c] = rowp[c]; s += v[c]; q += v[c] * v[c]; }
      s += __shfl_xor(s, 1); q += __shfl_xor(q, 1);
      s += __shfl_xor(s, 2); q += __shfl_xor(q, 2);
      float mean = s * (1.f / 96.f);
      float rs = rsqrtf(q * (1.f / 96.f) - mean * mean + 1e-5f);
      unsigned short ov[24];
      #pragma unroll
      for (int c = 0; c < 24; c++){
        int cc = part * 24 + c;
        ov[c] = f2bf((v[c] - mean) * rs * g1[cc] + b1n[cc]);
      }
      #pragma unroll
      for (int t = 0; t < 3; t++)
        *reinterpret_cast<bfrag8*>(&L[r * 104 + part * 24 + t * 8]) =
            *reinterpret_cast<const bfrag8*>(&ov[t * 8]);
    } else {
      bfrag8 z = {0, 0, 0, 0, 0, 0, 0, 0};
      #pragma unroll
      for (int t = 0; t < 3; t++)
        *reinterpret_cast<bfrag8*>(&L[r * 104 + part * 24 + t * 8]) = z;
    }
  }
  __syncthreads();   // As complete

  int wave = tid >> 6, lane = tid & 63;
  int ln = lane & 15, qd = lane >> 4;

  // A-fragments for ALL 4 row-tiles (48 VGPR) -> wqkv read once per block
  bfrag8 af[4][3];
  #pragma unroll
  for (int mt = 0; mt < 4; mt++)
    #pragma unroll
    for (int k3 = 0; k3 < 3; k3++)
      af[mt][k3] = *reinterpret_cast<const bfrag8*>(
          &L[(mt * 16 + ln) * 104 + k3 * 32 + qd * 8]);
  __syncthreads();   // As dead -> vt may overlay it; q/k writes may begin

  // ---- phase 1: qkv GEMM, N-split; q/k via swapped mfma -> b64 writes -------
  {
    int nct = (wave < 2) ? 5 : 4;
    for (int i = 0; i < nct; i++){
      int nt = wave + i * 4;
      int col0 = nt * 16;
      const unsigned short* wp = wqkv + (size_t)(col0 + ln) * 96 + qd * 8;
      bfrag8 B0 = *reinterpret_cast<const bfrag8*>(wp);
      bfrag8 B1 = *reinterpret_cast<const bfrag8*>(wp + 32);
      bfrag8 B2 = *reinterpret_cast<const bfrag8*>(wp + 64);
      if (nt < 12){
        // swapped: lane holds qkv^T[col0+qd*4+r][mt*16+ln] (4 consec d's)
        f32x4 bs4 = *reinterpret_cast<const f32x4*>(bqs + col0 + qd * 4);
        int c0 = (nt < 6) ? col0 : (col0 - 96);
        int base = 6656 + (c0 >> 5) * 4096 + ((nt < 6) ? 0 : 2048);
        int d0 = (c0 & 31) + qd * 4;
        #pragma unroll
        for (int mt = 0; mt < 4; mt++){
          f32x4 acc = bs4;
          acc = __builtin_amdgcn_mfma_f32_16x16x32_bf16(B0, af[mt][0], acc, 0, 0, 0);
          acc = __builtin_amdgcn_mfma_f32_16x16x32_bf16(B1, af[mt][1], acc, 0, 0, 0);
          acc = __builtin_amdgcn_mfma_f32_16x16x32_bf16(B2, af[mt][2], acc, 0, 0, 0);
          int m = mt * 16 + ln;
          *reinterpret_cast<u32x2*>(&L[base + swz32(m, d0)]) =
              pack4(acc[0], acc[1], acc[2], acc[3]);
        }
      } else {
        // v: original orientation, 4 consec n's at one d -> b64 into vt[d][n]
        int cc = col0 + ln - 192; int hh = cc >> 5, d = cc & 31;
        float bs = bqs[col0 + ln];
        #pragma unroll
        for (int mt = 0; mt < 4; mt++){
          f32x4 acc = {bs, bs, bs, bs};
          acc = __builtin_amdgcn_mfma_f32_16x16x32_bf16(af[mt][0], B0, acc, 0, 0, 0);
          acc = __builtin_amdgcn_mfma_f32_16x16x32_bf16(af[mt][1], B1, acc, 0, 0, 0);
          acc = __builtin_amdgcn_mfma_f32_16x16x32_bf16(af[mt][2], B2, acc, 0, 0, 0);
          int m0 = mt * 16 + qd * 4;
          *reinterpret_cast<u32x2*>(&L[hh * 2048 + swz64(d, m0)]) =
              pack4(acc[0], acc[1], acc[2], acc[3]);
        }
      }
    }
  }
  __syncthreads();

  // ---- phase 2+3: attention, head-private per wave (no internal barriers) ---
  int h = wave;
  if (wave < 3){
    bfrag8 qf[4];
    #pragma unroll
    for (int mt = 0; mt < 4; mt++)
      qf[mt] = *reinterpret_cast<const bfrag8*>(
          &L[6656 + h * 4096 + swz32(mt * 16 + ln, qd * 8)]);
    // QK^T with bias+mask (exp2 domain) as the MFMA C operand; 4-class table
    int wi = win & 255;
    int cls = (((wi >> 4) == 15) ? 2 : 0) | (((wi & 15) == 15) ? 1 : 0);
    const float* cbh = cbt + ((size_t)cls * 3 + h) * 4096;
    f32x4 sf[4][4];
    #pragma unroll
    for (int nt = 0; nt < 4; nt++){
      bfrag8 kf = *reinterpret_cast<const bfrag8*>(
          &L[6656 + h * 4096 + 2048 + swz32(nt * 16 + ln, qd * 8)]);
      #pragma unroll
      for (int mt = 0; mt < 4; mt++){
        f32x4 cv = *reinterpret_cast<const f32x4*>(
            cbh + mt * 1024 + nt * 256 + qd * 64 + ln * 4);
        sf[mt][nt] = __builtin_amdgcn_mfma_f32_16x16x32_bf16(qf[mt], kf, cv, 0, 0, 0);
      }
    }
    // softmax, exp2 domain, NO max subtraction (scores LN-bounded << 128;
    // invalid keys carry -1e4 -> exp2 -> 0). Mathematically exact in fp32.
    #pragma unroll
    for (int mt = 0; mt < 4; mt++){
      float sm[4];
      #pragma unroll
      for (int r = 0; r < 4; r++){
        float e0 = exp2f(sf[mt][0][r]);
        float e1 = exp2f(sf[mt][1][r]);
        float e2 = exp2f(sf[mt][2][r]);
        float e3 = exp2f(sf[mt][3][r]);
        sf[mt][0][r] = e0; sf[mt][1][r] = e1; sf[mt][2][r] = e2; sf[mt][3][r] = e3;
        sm[r] = e0 + e1 + e2 + e3;
      }
      #pragma unroll
      for (int r = 0; r < 4; r++)
        #pragma unroll
        for (int off = 1; off < 16; off <<= 1)
          sm[r] += __shfl_xor(sm[r], off);
      #pragma unroll
      for (int r = 0; r < 4; r++){
        float inv = __builtin_amdgcn_rcpf(sm[r]);
        int m = mt * 16 + qd * 4 + r;
        #pragma unroll
        for (int nt = 0; nt < 4; nt++)
          L[6656 + h * 4096 + swz64(m, nt * 16 + ln)] = f2bf(sf[mt][nt][r] * inv);
      }
    }

    // PV swapped: lane holds Os[m=mt*16+ln][d=dt*16+qd*4+r] -> b64 writes
    f32x4 of[4][2];
    #pragma unroll
    for (int mt = 0; mt < 4; mt++)
      #pragma unroll
      for (int dt = 0; dt < 2; dt++) of[mt][dt] = (f32x4){0.f, 0.f, 0.f, 0.f};
    #pragma unroll
    for (int k2 = 0; k2 < 2; k2++){
      bfrag8 vf[2];
      #pragma unroll
      for (int dt = 0; dt < 2; dt++)
        vf[dt] = *reinterpret_cast<const bfrag8*>(
            &L[h * 2048 + swz64(dt * 16 + ln, k2 * 32 + qd * 8)]);
      #pragma unroll
      for (int mt = 0; mt < 4; mt++){
        bfrag8 pf = *reinterpret_cast<const bfrag8*>(
            &L[6656 + h * 4096 + swz64(mt * 16 + ln, k2 * 32 + qd * 8)]);
        #pragma unroll
        for (int dt = 0; dt < 2; dt++)
          of[mt][dt] = __builtin_amdgcn_mfma_f32_16x16x32_bf16(vf[dt], pf, of[mt][dt], 0, 0, 0);
      }
    }
    #pragma unroll
    for (int mt = 0; mt < 4; mt++)
      #pragma unroll
      for (int dt = 0; dt < 2; dt++){
        int m = mt * 16 + ln, d0 = dt * 16 + qd * 4;
        *reinterpret_cast<u32x2*>(&L[h * 2048 + swz32(m, d0)]) =
            pack4(of[mt][dt][0], of[mt][dt][1], of[mt][dt][2], of[mt][dt][3]);
      }
  }
  __syncthreads();

  // ---- phase 4: proj GEMM swapped -> f32x4 Xf writes; bias via C-init -------
  {
    int rh = wave >> 1, nh = wave & 1;
    bfrag8 ap[2][3];
    #pragma unroll
    for (int mt2 = 0; mt2 < 2; mt2++)
      #pragma unroll
      for (int k3 = 0; k3 < 3; k3++)
        ap[mt2][k3] = *reinterpret_cast<const bfrag8*>(
            &L[k3 * 2048 + swz32(rh * 32 + mt2 * 16 + ln, qd * 8)]);
    float* Xf = reinterpret_cast<float*>(&L[6656]);   // 64x96 fp32, swizzled
    #pragma unroll
    for (int nt3 = 0; nt3 < 3; nt3++){
      int colb = (nh * 3 + nt3) * 16;
      const unsigned short* wp = wproj + (size_t)(colb + ln) * 96 + qd * 8;
      bfrag8 B0 = *reinterpret_cast<const bfrag8*>(wp);
      bfrag8 B1 = *reinterpret_cast<const bfrag8*>(wp + 32);
      bfrag8 B2 = *reinterpret_cast<const bfrag8*>(wp + 64);
      f32x4 bv4 = *reinterpret_cast<const f32x4*>(bproj + colb + qd * 4);
      #pragma unroll
      for (int mt2 = 0; mt2 < 2; mt2++){
        f32x4 acc = bv4;
        acc = __builtin_amdgcn_mfma_f32_16x16x32_bf16(B0, ap[mt2][0], acc, 0, 0, 0);
        acc = __builtin_amdgcn_mfma_f32_16x16x32_bf16(B1, ap[mt2][1], acc, 0, 0, 0);
        acc = __builtin_amdgcn_mfma_f32_16x16x32_bf16(B2, ap[mt2][2], acc, 0, 0, 0);
        int m = rh * 32 + mt2 * 16 + ln;
        *reinterpret_cast<f32x4*>(&Xf[fswz(m, colb + qd * 4)]) = acc;
      }
    }
  }
  __syncthreads();

  // ---- epilogue: residual + contiguous 48B/thread store ---------------------
  {
    int r = tid >> 2, part = tid & 3;
    if (r < 49){
      int gi = win_to_img(win * 49 + r);
      const float* Xf = reinterpret_cast<const float*>(&L[6656]);
      const float* rowp = x + (size_t)gi * 96 + part * 24;
      int sxm = (r & 7) << 2;
      unsigned short ov[24];
      #pragma unroll
      for (int t6 = 0; t6 < 6; t6++){
        int cc = part * 24 + t6 * 4;
        f32x4 pv = *reinterpret_cast<const f32x4*>(&Xf[r * 96 + (cc ^ sxm)]);
        f32x4 rv = *reinterpret_cast<const f32x4*>(&rowp[t6 * 4]);
        #pragma unroll
        for (int j = 0; j < 4; j++)
          ov[t6 * 4 + j] = f2bf(pv[j] + rv[j]);
      }
      unsigned short* dst = x2 + (size_t)gi * 96 + part * 24;
      #pragma unroll
      for (int t3 = 0; t3 < 3; t3++)
        *reinterpret_cast<bfrag8*>(dst + t3 * 8) =
            *reinterpret_cast<const bfrag8*>(&ov[t3 * 8]);
    }
  }
}

// ---- MLP: 32 rows/block, 6 waves, 25.1KB LDS -> 5 blocks/CU (30 waves) ------
__global__ __launch_bounds__(384, 4) void mlp_mfma_kernel(
    const unsigned short* __restrict__ x2,
    const float* __restrict__ g, const float* __restrict__ b,
    const unsigned short* __restrict__ w1, const float* __restrict__ b1,
    const unsigned short* __restrict__ w2, const float* __restrict__ b2,
    float* __restrict__ out)
{
  __shared__ unsigned short S[12544];   // Hs 32x392 (25.1KB); As 32x104 overlays
  unsigned short* As = S;
  unsigned short* Hs = S;
  int tid = threadIdx.x;
  int row0 = blockIdx.x * 32;

  // LN2 directly from global x2 (L2/LLC-resident) -> As, b128 writes
  if (tid < 128){
    int rr = tid >> 2, part = tid & 3;
    const unsigned short* rp = x2 + (size_t)(row0 + rr) * 96 + part * 24;
    float v[24]; float s = 0.f, q = 0.f;
    #pragma unroll
    for (int t = 0; t < 3; t++){
      bfrag8 w = *reinterpret_cast<const bfrag8*>(rp + t * 8);
      #pragma unroll
      for (int j = 0; j < 8; j++){
        float f = bf2f((unsigned short)w[j]);
        v[t * 8 + j] = f; s += f; q += f * f;
      }
    }
    s += __shfl_xor(s, 1); q += __shfl_xor(q, 1);
    s += __shfl_xor(s, 2); q += __shfl_xor(q, 2);
    float mean = s * (1.f / 96.f);
    float rs = rsqrtf(q * (1.f / 96.f) - mean * mean + 1e-5f);
    unsigned short ov[24];
    #pragma unroll
    for (int c = 0; c < 24; c++){
      int cc = part * 24 + c;
      ov[c] = f2bf((v[c] - mean) * rs * g[cc] + b[cc]);
    }
    #pragma unroll
    for (int t = 0; t < 3; t++)
      *reinterpret_cast<bfrag8*>(&As[rr * 104 + part * 24 + t * 8]) =
          *reinterpret_cast<const bfrag8*>(&ov[t * 8]);
  }
  __syncthreads();

  int wave = tid / 64, lane = tid & 63;
  int ln = lane & 15, qd = lane >> 4;

  bfrag8 af[2][3];
  #pragma unroll
  for (int mt = 0; mt < 2; mt++)
    #pragma unroll
    for (int k3 = 0; k3 < 3; k3++)
      af[mt][k3] = *reinterpret_cast<const bfrag8*>(
          &As[(mt * 16 + ln) * 104 + k3 * 32 + qd * 8]);
  __syncthreads();   // As dead -> Hs writes may proceed

  // fc1 N-split, swapped mfma: wave owns ntl = wave, +6, +12, +18 -> b64 Hs
  for (int i = 0; i < 4; i++){
    int ntl = wave + i * 6;
    int col0 = ntl * 16;
    const unsigned short* wp = w1 + (size_t)(col0 + ln) * 96 + qd * 8;
    bfrag8 B0 = *reinterpret_cast<const bfrag8*>(wp);
    bfrag8 B1 = *reinterpret_cast<const bfrag8*>(wp + 32);
    bfrag8 B2 = *reinterpret_cast<const bfrag8*>(wp + 64);
    f32x4 bs4 = *reinterpret_cast<const f32x4*>(b1 + col0 + qd * 4);
    #pragma unroll
    for (int mt = 0; mt < 2; mt++){
      f32x4 a = bs4;
      a = __builtin_amdgcn_mfma_f32_16x16x32_bf16(B0, af[mt][0], a, 0, 0, 0);
      a = __builtin_amdgcn_mfma_f32_16x16x32_bf16(B1, af[mt][1], a, 0, 0, 0);
      a = __builtin_amdgcn_mfma_f32_16x16x32_bf16(B2, af[mt][2], a, 0, 0, 0);
      int m = mt * 16 + ln;
      *reinterpret_cast<u32x2*>(&Hs[m * 392 + col0 + qd * 4]) =
          pack4(gelu_f(a[0]), gelu_f(a[1]), gelu_f(a[2]), gelu_f(a[3]));
    }
  }
  __syncthreads();

  // fc2 N-split, swapped mfma: wave owns out cols wave*16..+15
  int col0 = wave * 16;
  f32x4 bs4 = *reinterpret_cast<const f32x4*>(b2 + col0 + qd * 4);
  f32x4 acc[2];
  #pragma unroll
  for (int mt = 0; mt < 2; mt++) acc[mt] = bs4;
  for (int k2 = 0; k2 < 12; k2++){
    bfrag8 B = *reinterpret_cast<const bfrag8*>(
        w2 + (size_t)(col0 + ln) * 384 + k2 * 32 + qd * 8);
    #pragma unroll
    for (int mt = 0; mt < 2; mt++){
      bfrag8 p = *reinterpret_cast<const bfrag8*>(
          &Hs[(mt * 16 + ln) * 392 + k2 * 32 + qd * 8]);
      acc[mt] = __builtin_amdgcn_mfma_f32_16x16x32_bf16(B, p, acc[mt], 0, 0, 0);
    }
  }
  {
    #pragma unroll
    for (int mt = 0; mt < 2; mt++){
      int grow = row0 + mt * 16 + ln;
      u32x2 rv = *reinterpret_cast<const u32x2*>(
          x2 + (size_t)grow * 96 + col0 + qd * 4);
      f32x4 o;
      o[0] = acc[mt][0] + bf2f((unsigned short)(rv.x & 0xffff));
      o[1] = acc[mt][1] + bf2f((unsigned short)(rv.x >> 16));
      o[2] = acc[mt][2] + bf2f((unsigned short)(rv.y & 0xffff));
      o[3] = acc[mt][3] + bf2f((unsigned short)(rv.y >> 16));
      *reinterpret_cast<f32x4*>(out + (size_t)grow * 96 + col0 + qd * 4) = o;
    }
  }
}

extern "C" void kernel_launch(void* const* d_in, const int* in_sizes, int n_in,
                              void* d_out, int out_size, void* d_ws, size_t ws_size,
                              hipStream_t stream)
{
  const float* x      = (const float*)d_in[0];
  const float* mask   = (const float*)d_in[1];
  const float* n1g    = (const float*)d_in[2];
  const float* n1b    = (const float*)d_in[3];
  const float* qkv_w  = (const float*)d_in[4];
  const float* qkv_b  = (const float*)d_in[5];
  const float* relt   = (const float*)d_in[6];
  const float* proj_w = (const float*)d_in[7];
  const float* proj_b = (const float*)d_in[8];
  const float* n2g    = (const float*)d_in[9];
  const float* n2b    = (const float*)d_in[10];
  const float* fc1_w  = (const float*)d_in[11];
  const float* fc1_b  = (const float*)d_in[12];
  const float* fc2_w  = (const float*)d_in[13];
  const float* fc2_b  = (const float*)d_in[14];
  float* outp = (float*)d_out;
  (void)in_sizes; (void)n_in; (void)out_size; (void)ws_size; (void)mask;

  const size_t M = 200704;
  char* ws = (char*)d_ws;
  unsigned short* x2     = (unsigned short*)ws;              // 38.5 MB
  size_t o = M * 96 * 2;
  unsigned short* w1bf   = (unsigned short*)(ws + o); o += 384 * 96 * 2;
  unsigned short* w2bf   = (unsigned short*)(ws + o); o += 96 * 384 * 2;
  unsigned short* wqkvbf = (unsigned short*)(ws + o); o += 288 * 96 * 2;
  unsigned short* wprojbf= (unsigned short*)(ws + o); o += 96 * 96 * 2;
  float*          bqs    = (float*)(ws + o);          o += 288 * 4 + 64;
  float*          cbuf   = (float*)(ws + o); o += (size_t)4 * 3 * 4096 * 4;  // 196 KB

  cvt_all_kernel<<<434, 256, 0, stream>>>(
      fc1_w, w1bf, fc2_w, w2bf, qkv_w, wqkvbf, proj_w, wprojbf, qkv_b, bqs);
  cb_kernel<<<192, 256, 0, stream>>>(relt, mask, cbuf);
  fused_win_kernel<<<4096, 256, 0, stream>>>(
      x, n1g, n1b, wqkvbf, bqs, cbuf, wprojbf, proj_b, x2);
  mlp_mfma_kernel<<<6272, 384, 0, stream>>>(
      x2, n2g, n2b, w1bf, fc1_b, w2bf, fc2_b, outp);
}

// Round 10
// 298.830 us; speedup vs baseline: 1.0865x; 1.0865x over previous
//
#include <hip/hip_runtime.h>
#include <hip/hip_bf16.h>
#include <math.h>

// Swin block, MI355X round 16: fused = R8/R14 frozen (best measured). mlp
// reverted to R8's 64-row structure (99us known) + ONE change: split-K
// software pipeline. H split into halves (cols 0-191 / 192-383):
// fc1-h0 -> bar -> {fc1-h1 || fc2-h0 interleaved} -> bar -> fc2-h1.
// Rationale: R8 (instr cut null) + R9 (occupancy up, perf down) falsified
// issue- and occupancy-bound models for mlp -> phase-chain bound. The merged
// middle region co-schedules fc1's VALU/GELU with fc2's DS/MFMA in-wave.

typedef __attribute__((ext_vector_type(8))) short bfrag8;   // 8 bf16 = 4 VGPRs
typedef __attribute__((ext_vector_type(4))) float f32x4;
typedef __attribute__((ext_vector_type(2))) unsigned int u32x2;

#define LOG2E 1.4426950408889634f

__device__ __forceinline__ float bf2f(unsigned short u){
  union { unsigned int i; float f; } c; c.i = ((unsigned int)u) << 16; return c.f;
}
__device__ __forceinline__ unsigned short f2bf(float f){
  __hip_bfloat16 h = __float2bfloat16(f);
  union { __hip_bfloat16 h; unsigned short u; } c; c.h = h; return c.u;
}
__device__ __forceinline__ u32x2 pack4(float a0, float a1, float a2, float a3){
  u32x2 r;
  r.x = (unsigned int)f2bf(a0) | ((unsigned int)f2bf(a1) << 16);
  r.y = (unsigned int)f2bf(a2) | ((unsigned int)f2bf(a3) << 16);
  return r;
}
// gelu(x) ~ x * sigmoid(1.5957691(x + 0.044715 x^3)), exp2-folded:
// x / (1 + exp2(x*(c1 + c2*x^2))), c1 = -1.5957691*log2e, c2 = c1*0.044715
__device__ __forceinline__ float gelu_f(float x){
  const float c1 = -2.302208198f, c2 = -0.1029432397f;
  float x2 = x * x;
  float t  = __builtin_fmaf(x2, c2, c1);
  float u  = exp2f(x * t);
  return x * __builtin_amdgcn_rcpf(1.f + u);
}

// 32-ush rows: granule xor (4 qd classes distinct); XOR bits 3-4 only ->
// 4-aligned groups stay contiguous (b64-safe).
__device__ __forceinline__ int swz32(int r, int c){
  return r * 32 + (c ^ (((r ^ (r >> 2)) & 3) << 3));
}
// 64-ush rows: granule xor bits 3-5; 4-aligned groups stay contiguous.
__device__ __forceinline__ int swz64(int r, int c){
  return r * 64 + (c ^ (((r ^ (r >> 3)) & 7) << 3));
}
// fp32 proj-output buffer (stride 96 floats): xor bits 2-4 by row; 4-float
// groups stay contiguous (f32x4-safe).
__device__ __forceinline__ int fswz(int r, int c){
  return r * 96 + (c ^ ((r & 7) << 2));
}

// window-order row r (win*49+n) -> image row (b*12544 + h*112 + w), shift +3.
__device__ __forceinline__ int win_to_img(int r){
  int win = r / 49, n = r - win * 49;
  int b  = win >> 8, wi = win & 255;
  int wh = wi >> 4,  ww = wi & 15;
  int i  = n / 7,    j  = n - i * 7;
  int hs = wh * 7 + i + 3; if (hs >= 112) hs -= 112;
  int ws = ww * 7 + j + 3; if (ws >= 112) ws -= 112;
  return b * 12544 + hs * 112 + ws;
}

// ---- weight conversions + scaled qkv bias in one kernel ---------------------
__global__ __launch_bounds__(256) void cvt_all_kernel(
    const float* __restrict__ s1, unsigned short* __restrict__ d1,   // 36864
    const float* __restrict__ s2, unsigned short* __restrict__ d2,   // 36864
    const float* __restrict__ s3, unsigned short* __restrict__ d3,   // 27648
    const float* __restrict__ s4, unsigned short* __restrict__ d4,   // 9216
    const float* __restrict__ bq, float* __restrict__ bqs)           // 288
{
  const float QS = 0.17677669529663687f * 1.4426950408889634f;
  int i = blockIdx.x * 256 + threadIdx.x;
  if      (i < 36864)  d1[i]          = f2bf(s1[i]);
  else if (i < 73728)  d2[i - 36864]  = f2bf(s2[i - 36864]);
  else if (i < 101376){
    int j = i - 73728;
    float v = s3[j];
    if (j < 9216) v *= QS;          // q rows: col < 96
    d3[j] = f2bf(v);
  }
  else if (i < 110592) d4[i - 101376] = f2bf(s4[i - 101376]);
  else if (i < 110880){
    int j = i - 110592;
    float v = bq[j];
    if (j < 96) v *= QS;
    bqs[j] = v;
  }
}

// ---- rel-bias + shift-mask table, 4 window classes, MFMA-fragment layout ----
// cbt[cls][h][mt][nt][qd][ln][r] fp32 * log2e; n>=49 -> -1e4, invalid m -> 0.
// cls: 0 interior, 1 ww=15, 2 wh=15, 3 corner (only 4 distinct Swin masks).
__global__ __launch_bounds__(256) void cb_kernel(
    const float* __restrict__ relt, const float* __restrict__ mask,
    float* __restrict__ cbt)
{
  int idx = blockIdx.x * 256 + threadIdx.x;      // 4*3*4096 = 49152 total
  int ch = idx >> 12;
  int cls = ch / 3, h = ch - cls * 3;
  int w = (cls == 0) ? 0 : (cls == 1) ? 15 : (cls == 2) ? 240 : 255;
  int rem = idx & 4095;
  int mt = rem >> 10, nt = (rem >> 8) & 3, qd = (rem >> 6) & 3;
  int ln = (rem >> 2) & 15, r = rem & 3;
  int m = mt * 16 + qd * 4 + r, n = nt * 16 + ln;
  float v;
  if (m < 49 && n < 49){
    int i1 = m / 7, j1 = m - i1 * 7;
    int i2 = n / 7, j2 = n - i2 * 7;
    int ridx = (i1 - i2 + 6) * 13 + (j1 - j2 + 6);
    v = (relt[ridx * 3 + h] + mask[w * 2401 + m * 49 + n]) * LOG2E;
  } else if (n >= 49) v = -10000.0f;
  else v = 0.0f;
  cbt[idx] = v;
}

// ---- fused per-window kernel: LN1 + qkv + attention + proj ------------------
// LDS 37.9KB: As[0,6656) -> vt/Os[0,6144) overlay; q/k/Ps per head at
// [6656+h*4096); Xf (fp32 64x96) overlays q/k/Ps at [6656,18944) in phase 4.
__global__ __launch_bounds__(256, 4) void fused_win_kernel(
    const float* __restrict__ x,
    const float* __restrict__ g1, const float* __restrict__ b1n,
    const unsigned short* __restrict__ wqkv, const float* __restrict__ bqs,
    const float* __restrict__ cbt,
    const unsigned short* __restrict__ wproj, const float* __restrict__ bproj,
    unsigned short* __restrict__ x2)
{
  __shared__ unsigned short L[18944];   // 37888 B

  int win = blockIdx.x, tid = threadIdx.x;

  // ---- phase 0: stage + LN1 -> As @ [0, 6656), b128 writes ------------------
  {
    int r = tid >> 2, part = tid & 3;
    if (r < 49){
      int gr = win_to_img(win * 49 + r);
      const float* rowp = x + (size_t)gr * 96 + part * 24;
      float v[24]; float s = 0.f, q = 0.f;
      #pragma unroll
      for (int c = 0; c < 24; c++){ v[c] = rowp[c]; s += v[c]; q += v[c] * v[c]; }
      s += __shfl_xor(s, 1); q += __shfl_xor(q, 1);
      s += __shfl_xor(s, 2); q += __shfl_xor(q, 2);
      float mean = s * (1.f / 96.f);
      float rs = rsqrtf(q * (1.f / 96.f) - mean * mean + 1e-5f);
      unsigned short ov[24];
      #pragma unroll
      for (int c = 0; c < 24; c++){
        int cc = part * 24 + c;
        ov[c] = f2bf((v[c] - mean) * rs * g1[cc] + b1n[cc]);
      }
      #pragma unroll
      for (int t = 0; t < 3; t++)
        *reinterpret_cast<bfrag8*>(&L[r * 104 + part * 24 + t * 8]) =
            *reinterpret_cast<const bfrag8*>(&ov[t * 8]);
    } else {
      bfrag8 z = {0, 0, 0, 0, 0, 0, 0, 0};
      #pragma unroll
      for (int t = 0; t < 3; t++)
        *reinterpret_cast<bfrag8*>(&L[r * 104 + part * 24 + t * 8]) = z;
    }
  }
  __syncthreads();   // As complete

  int wave = tid >> 6, lane = tid & 63;
  int ln = lane & 15, qd = lane >> 4;

  // A-fragments for ALL 4 row-tiles (48 VGPR) -> wqkv read once per block
  bfrag8 af[4][3];
  #pragma unroll
  for (int mt = 0; mt < 4; mt++)
    #pragma unroll
    for (int k3 = 0; k3 < 3; k3++)
      af[mt][k3] = *reinterpret_cast<const bfrag8*>(
          &L[(mt * 16 + ln) * 104 + k3 * 32 + qd * 8]);
  __syncthreads();   // As dead -> vt may overlay it; q/k writes may begin

  // ---- phase 1: qkv GEMM, N-split; q/k via swapped mfma -> b64 writes -------
  {
    int nct = (wave < 2) ? 5 : 4;
    for (int i = 0; i < nct; i++){
      int nt = wave + i * 4;
      int col0 = nt * 16;
      const unsigned short* wp = wqkv + (size_t)(col0 + ln) * 96 + qd * 8;
      bfrag8 B0 = *reinterpret_cast<const bfrag8*>(wp);
      bfrag8 B1 = *reinterpret_cast<const bfrag8*>(wp + 32);
      bfrag8 B2 = *reinterpret_cast<const bfrag8*>(wp + 64);
      if (nt < 12){
        // swapped: lane holds qkv^T[col0+qd*4+r][mt*16+ln] (4 consec d's)
        f32x4 bs4 = *reinterpret_cast<const f32x4*>(bqs + col0 + qd * 4);
        int c0 = (nt < 6) ? col0 : (col0 - 96);
        int base = 6656 + (c0 >> 5) * 4096 + ((nt < 6) ? 0 : 2048);
        int d0 = (c0 & 31) + qd * 4;
        #pragma unroll
        for (int mt = 0; mt < 4; mt++){
          f32x4 acc = bs4;
          acc = __builtin_amdgcn_mfma_f32_16x16x32_bf16(B0, af[mt][0], acc, 0, 0, 0);
          acc = __builtin_amdgcn_mfma_f32_16x16x32_bf16(B1, af[mt][1], acc, 0, 0, 0);
          acc = __builtin_amdgcn_mfma_f32_16x16x32_bf16(B2, af[mt][2], acc, 0, 0, 0);
          int m = mt * 16 + ln;
          *reinterpret_cast<u32x2*>(&L[base + swz32(m, d0)]) =
              pack4(acc[0], acc[1], acc[2], acc[3]);
        }
      } else {
        // v: original orientation, 4 consec n's at one d -> b64 into vt[d][n]
        int cc = col0 + ln - 192; int hh = cc >> 5, d = cc & 31;
        float bs = bqs[col0 + ln];
        #pragma unroll
        for (int mt = 0; mt < 4; mt++){
          f32x4 acc = {bs, bs, bs, bs};
          acc = __builtin_amdgcn_mfma_f32_16x16x32_bf16(af[mt][0], B0, acc, 0, 0, 0);
          acc = __builtin_amdgcn_mfma_f32_16x16x32_bf16(af[mt][1], B1, acc, 0, 0, 0);
          acc = __builtin_amdgcn_mfma_f32_16x16x32_bf16(af[mt][2], B2, acc, 0, 0, 0);
          int m0 = mt * 16 + qd * 4;
          *reinterpret_cast<u32x2*>(&L[hh * 2048 + swz64(d, m0)]) =
              pack4(acc[0], acc[1], acc[2], acc[3]);
        }
      }
    }
  }
  __syncthreads();

  // ---- phase 2+3: attention, head-private per wave (no internal barriers) ---
  int h = wave;
  if (wave < 3){
    bfrag8 qf[4];
    #pragma unroll
    for (int mt = 0; mt < 4; mt++)
      qf[mt] = *reinterpret_cast<const bfrag8*>(
          &L[6656 + h * 4096 + swz32(mt * 16 + ln, qd * 8)]);
    // QK^T with bias+mask (exp2 domain) as the MFMA C operand; 4-class table
    int wi = win & 255;
    int cls = (((wi >> 4) == 15) ? 2 : 0) | (((wi & 15) == 15) ? 1 : 0);
    const float* cbh = cbt + ((size_t)cls * 3 + h) * 4096;
    f32x4 sf[4][4];
    #pragma unroll
    for (int nt = 0; nt < 4; nt++){
      bfrag8 kf = *reinterpret_cast<const bfrag8*>(
          &L[6656 + h * 4096 + 2048 + swz32(nt * 16 + ln, qd * 8)]);
      #pragma unroll
      for (int mt = 0; mt < 4; mt++){
        f32x4 cv = *reinterpret_cast<const f32x4*>(
            cbh + mt * 1024 + nt * 256 + qd * 64 + ln * 4);
        sf[mt][nt] = __builtin_amdgcn_mfma_f32_16x16x32_bf16(qf[mt], kf, cv, 0, 0, 0);
      }
    }
    // softmax, exp2 domain, NO max subtraction (scores LN-bounded << 128;
    // invalid keys carry -1e4 -> exp2 -> 0). Mathematically exact in fp32.
    #pragma unroll
    for (int mt = 0; mt < 4; mt++){
      float sm[4];
      #pragma unroll
      for (int r = 0; r < 4; r++){
        float e0 = exp2f(sf[mt][0][r]);
        float e1 = exp2f(sf[mt][1][r]);
        float e2 = exp2f(sf[mt][2][r]);
        float e3 = exp2f(sf[mt][3][r]);
        sf[mt][0][r] = e0; sf[mt][1][r] = e1; sf[mt][2][r] = e2; sf[mt][3][r] = e3;
        sm[r] = e0 + e1 + e2 + e3;
      }
      #pragma unroll
      for (int r = 0; r < 4; r++)
        #pragma unroll
        for (int off = 1; off < 16; off <<= 1)
          sm[r] += __shfl_xor(sm[r], off);
      #pragma unroll
      for (int r = 0; r < 4; r++){
        float inv = __builtin_amdgcn_rcpf(sm[r]);
        int m = mt * 16 + qd * 4 + r;
        #pragma unroll
        for (int nt = 0; nt < 4; nt++)
          L[6656 + h * 4096 + swz64(m, nt * 16 + ln)] = f2bf(sf[mt][nt][r] * inv);
      }
    }

    // PV swapped: lane holds Os[m=mt*16+ln][d=dt*16+qd*4+r] -> b64 writes
    f32x4 of[4][2];
    #pragma unroll
    for (int mt = 0; mt < 4; mt++)
      #pragma unroll
      for (int dt = 0; dt < 2; dt++) of[mt][dt] = (f32x4){0.f, 0.f, 0.f, 0.f};
    #pragma unroll
    for (int k2 = 0; k2 < 2; k2++){
      bfrag8 vf[2];
      #pragma unroll
      for (int dt = 0; dt < 2; dt++)
        vf[dt] = *reinterpret_cast<const bfrag8*>(
            &L[h * 2048 + swz64(dt * 16 + ln, k2 * 32 + qd * 8)]);
      #pragma unroll
      for (int mt = 0; mt < 4; mt++){
        bfrag8 pf = *reinterpret_cast<const bfrag8*>(
            &L[6656 + h * 4096 + swz64(mt * 16 + ln, k2 * 32 + qd * 8)]);
        #pragma unroll
        for (int dt = 0; dt < 2; dt++)
          of[mt][dt] = __builtin_amdgcn_mfma_f32_16x16x32_bf16(vf[dt], pf, of[mt][dt], 0, 0, 0);
      }
    }
    #pragma unroll
    for (int mt = 0; mt < 4; mt++)
      #pragma unroll
      for (int dt = 0; dt < 2; dt++){
        int m = mt * 16 + ln, d0 = dt * 16 + qd * 4;
        *reinterpret_cast<u32x2*>(&L[h * 2048 + swz32(m, d0)]) =
            pack4(of[mt][dt][0], of[mt][dt][1], of[mt][dt][2], of[mt][dt][3]);
      }
  }
  __syncthreads();

  // ---- phase 4: proj GEMM swapped -> f32x4 Xf writes; bias via C-init -------
  {
    int rh = wave >> 1, nh = wave & 1;
    bfrag8 ap[2][3];
    #pragma unroll
    for (int mt2 = 0; mt2 < 2; mt2++)
      #pragma unroll
      for (int k3 = 0; k3 < 3; k3++)
        ap[mt2][k3] = *reinterpret_cast<const bfrag8*>(
            &L[k3 * 2048 + swz32(rh * 32 + mt2 * 16 + ln, qd * 8)]);
    float* Xf = reinterpret_cast<float*>(&L[6656]);   // 64x96 fp32, swizzled
    #pragma unroll
    for (int nt3 = 0; nt3 < 3; nt3++){
      int colb = (nh * 3 + nt3) * 16;
      const unsigned short* wp = wproj + (size_t)(colb + ln) * 96 + qd * 8;
      bfrag8 B0 = *reinterpret_cast<const bfrag8*>(wp);
      bfrag8 B1 = *reinterpret_cast<const bfrag8*>(wp + 32);
      bfrag8 B2 = *reinterpret_cast<const bfrag8*>(wp + 64);
      f32x4 bv4 = *reinterpret_cast<const f32x4*>(bproj + colb + qd * 4);
      #pragma unroll
      for (int mt2 = 0; mt2 < 2; mt2++){
        f32x4 acc = bv4;
        acc = __builtin_amdgcn_mfma_f32_16x16x32_bf16(B0, ap[mt2][0], acc, 0, 0, 0);
        acc = __builtin_amdgcn_mfma_f32_16x16x32_bf16(B1, ap[mt2][1], acc, 0, 0, 0);
        acc = __builtin_amdgcn_mfma_f32_16x16x32_bf16(B2, ap[mt2][2], acc, 0, 0, 0);
        int m = rh * 32 + mt2 * 16 + ln;
        *reinterpret_cast<f32x4*>(&Xf[fswz(m, colb + qd * 4)]) = acc;
      }
    }
  }
  __syncthreads();

  // ---- epilogue: residual + contiguous 48B/thread store ---------------------
  {
    int r = tid >> 2, part = tid & 3;
    if (r < 49){
      int gi = win_to_img(win * 49 + r);
      const float* Xf = reinterpret_cast<const float*>(&L[6656]);
      const float* rowp = x + (size_t)gi * 96 + part * 24;
      int sxm = (r & 7) << 2;
      unsigned short ov[24];
      #pragma unroll
      for (int t6 = 0; t6 < 6; t6++){
        int cc = part * 24 + t6 * 4;
        f32x4 pv = *reinterpret_cast<const f32x4*>(&Xf[r * 96 + (cc ^ sxm)]);
        f32x4 rv = *reinterpret_cast<const f32x4*>(&rowp[t6 * 4]);
        #pragma unroll
        for (int j = 0; j < 4; j++)
          ov[t6 * 4 + j] = f2bf(pv[j] + rv[j]);
      }
      unsigned short* dst = x2 + (size_t)gi * 96 + part * 24;
      #pragma unroll
      for (int t3 = 0; t3 < 3; t3++)
        *reinterpret_cast<bfrag8*>(dst + t3 * 8) =
            *reinterpret_cast<const bfrag8*>(&ov[t3 * 8]);
    }
  }
}

// ---- MLP: 64 rows/block, 6 waves, split-K pipeline (fc1-h1 || fc2-h0) -------
__global__ __launch_bounds__(384, 4) void mlp_mfma_kernel(
    const unsigned short* __restrict__ x2,
    const float* __restrict__ g, const float* __restrict__ b,
    const unsigned short* __restrict__ w1, const float* __restrict__ b1,
    const unsigned short* __restrict__ w2, const float* __restrict__ b2,
    float* __restrict__ out)
{
  __shared__ unsigned short S[25088];   // Hs 64x392 (50.2KB); As 64x104 overlays
  unsigned short* As = S;
  unsigned short* Hs = S;
  int tid = threadIdx.x;
  int row0 = blockIdx.x * 64;

  // LN2 directly from global x2 (L2/LLC-resident) -> As, b128 writes
  if (tid < 256){
    int rr = tid >> 2, part = tid & 3;
    const unsigned short* rp = x2 + (size_t)(row0 + rr) * 96 + part * 24;
    float v[24]; float s = 0.f, q = 0.f;
    #pragma unroll
    for (int t = 0; t < 3; t++){
      bfrag8 w = *reinterpret_cast<const bfrag8*>(rp + t * 8);
      #pragma unroll
      for (int j = 0; j < 8; j++){
        float f = bf2f((unsigned short)w[j]);
        v[t * 8 + j] = f; s += f; q += f * f;
      }
    }
    s += __shfl_xor(s, 1); q += __shfl_xor(q, 1);
    s += __shfl_xor(s, 2); q += __shfl_xor(q, 2);
    float mean = s * (1.f / 96.f);
    float rs = rsqrtf(q * (1.f / 96.f) - mean * mean + 1e-5f);
    unsigned short ov[24];
    #pragma unroll
    for (int c = 0; c < 24; c++){
      int cc = part * 24 + c;
      ov[c] = f2bf((v[c] - mean) * rs * g[cc] + b[cc]);
    }
    #pragma unroll
    for (int t = 0; t < 3; t++)
      *reinterpret_cast<bfrag8*>(&As[rr * 104 + part * 24 + t * 8]) =
          *reinterpret_cast<const bfrag8*>(&ov[t * 8]);
  }
  __syncthreads();

  int wave = tid / 64, lane = tid & 63;
  int ln = lane & 15, qd = lane >> 4;

  bfrag8 af[4][3];
  #pragma unroll
  for (int mt = 0; mt < 4; mt++)
    #pragma unroll
    for (int k3 = 0; k3 < 3; k3++)
      af[mt][k3] = *reinterpret_cast<const bfrag8*>(
          &As[(mt * 16 + ln) * 104 + k3 * 32 + qd * 8]);
  __syncthreads();   // As dead -> Hs writes may proceed

  // fc1 half0: ntl = wave, wave+6 (H cols 0..191) -> b64 Hs writes
  #pragma unroll
  for (int i = 0; i < 2; i++){
    int ntl = wave + i * 6;
    int col0 = ntl * 16;
    const unsigned short* wp = w1 + (size_t)(col0 + ln) * 96 + qd * 8;
    bfrag8 B0 = *reinterpret_cast<const bfrag8*>(wp);
    bfrag8 B1 = *reinterpret_cast<const bfrag8*>(wp + 32);
    bfrag8 B2 = *reinterpret_cast<const bfrag8*>(wp + 64);
    f32x4 bs4 = *reinterpret_cast<const f32x4*>(b1 + col0 + qd * 4);
    #pragma unroll
    for (int mt = 0; mt < 4; mt++){
      f32x4 a = bs4;
      a = __builtin_amdgcn_mfma_f32_16x16x32_bf16(B0, af[mt][0], a, 0, 0, 0);
      a = __builtin_amdgcn_mfma_f32_16x16x32_bf16(B1, af[mt][1], a, 0, 0, 0);
      a = __builtin_amdgcn_mfma_f32_16x16x32_bf16(B2, af[mt][2], a, 0, 0, 0);
      int m = mt * 16 + ln;
      *reinterpret_cast<u32x2*>(&Hs[m * 392 + col0 + qd * 4]) =
          pack4(gelu_f(a[0]), gelu_f(a[1]), gelu_f(a[2]), gelu_f(a[3]));
    }
  }
  __syncthreads();   // H cols 0..191 complete

  // fc2 accumulator (out cols wave*16..+15, swapped layout)
  int oc0 = wave * 16;
  f32x4 obs4 = *reinterpret_cast<const f32x4*>(b2 + oc0 + qd * 4);
  f32x4 acc[4];
  #pragma unroll
  for (int mt = 0; mt < 4; mt++) acc[mt] = obs4;

  // middle region: fc1 half1 (cols 192..383, disjoint from fc2-h0 reads)
  // interleaved with fc2 half0 (k2 = 0..5) -> VALU/GELU overlaps DS/MFMA
  #pragma unroll
  for (int i = 0; i < 2; i++){
    {
      int ntl = wave + 12 + i * 6;
      int col0 = ntl * 16;
      const unsigned short* wp = w1 + (size_t)(col0 + ln) * 96 + qd * 8;
      bfrag8 B0 = *reinterpret_cast<const bfrag8*>(wp);
      bfrag8 B1 = *reinterpret_cast<const bfrag8*>(wp + 32);
      bfrag8 B2 = *reinterpret_cast<const bfrag8*>(wp + 64);
      f32x4 bs4 = *reinterpret_cast<const f32x4*>(b1 + col0 + qd * 4);
      #pragma unroll
      for (int mt = 0; mt < 4; mt++){
        f32x4 a = bs4;
        a = __builtin_amdgcn_mfma_f32_16x16x32_bf16(B0, af[mt][0], a, 0, 0, 0);
        a = __builtin_amdgcn_mfma_f32_16x16x32_bf16(B1, af[mt][1], a, 0, 0, 0);
        a = __builtin_amdgcn_mfma_f32_16x16x32_bf16(B2, af[mt][2], a, 0, 0, 0);
        int m = mt * 16 + ln;
        *reinterpret_cast<u32x2*>(&Hs[m * 392 + col0 + qd * 4]) =
            pack4(gelu_f(a[0]), gelu_f(a[1]), gelu_f(a[2]), gelu_f(a[3]));
      }
    }
    #pragma unroll
    for (int k2 = i * 3; k2 < i * 3 + 3; k2++){
      bfrag8 B = *reinterpret_cast<const bfrag8*>(
          w2 + (size_t)(oc0 + ln) * 384 + k2 * 32 + qd * 8);
      #pragma unroll
      for (int mt = 0; mt < 4; mt++){
        bfrag8 p = *reinterpret_cast<const bfrag8*>(
            &Hs[(mt * 16 + ln) * 392 + k2 * 32 + qd * 8]);
        acc[mt] = __builtin_amdgcn_mfma_f32_16x16x32_bf16(B, p, acc[mt], 0, 0, 0);
      }
    }
  }
  __syncthreads();   // H cols 192..383 complete

  // fc2 half1: k2 = 6..11
  #pragma unroll
  for (int k2 = 6; k2 < 12; k2++){
    bfrag8 B = *reinterpret_cast<const bfrag8*>(
        w2 + (size_t)(oc0 + ln) * 384 + k2 * 32 + qd * 8);
    #pragma unroll
    for (int mt = 0; mt < 4; mt++){
      bfrag8 p = *reinterpret_cast<const bfrag8*>(
          &Hs[(mt * 16 + ln) * 392 + k2 * 32 + qd * 8]);
      acc[mt] = __builtin_amdgcn_mfma_f32_16x16x32_bf16(B, p, acc[mt], 0, 0, 0);
    }
  }

  // epilogue: residual (b64 x2 loads) + dwordx4 out stores
  {
    #pragma unroll
    for (int mt = 0; mt < 4; mt++){
      int grow = row0 + mt * 16 + ln;
      u32x2 rv = *reinterpret_cast<const u32x2*>(
          x2 + (size_t)grow * 96 + oc0 + qd * 4);
      f32x4 o;
      o[0] = acc[mt][0] + bf2f((unsigned short)(rv.x & 0xffff));
      o[1] = acc[mt][1] + bf2f((unsigned short)(rv.x >> 16));
      o[2] = acc[mt][2] + bf2f((unsigned short)(rv.y & 0xffff));
      o[3] = acc[mt][3] + bf2f((unsigned short)(rv.y >> 16));
      *reinterpret_cast<f32x4*>(out + (size_t)grow * 96 + oc0 + qd * 4) = o;
    }
  }
}

extern "C" void kernel_launch(void* const* d_in, const int* in_sizes, int n_in,
                              void* d_out, int out_size, void* d_ws, size_t ws_size,
                              hipStream_t stream)
{
  const float* x      = (const float*)d_in[0];
  const float* mask   = (const float*)d_in[1];
  const float* n1g    = (const float*)d_in[2];
  const float* n1b    = (const float*)d_in[3];
  const float* qkv_w  = (const float*)d_in[4];
  const float* qkv_b  = (const float*)d_in[5];
  const float* relt   = (const float*)d_in[6];
  const float* proj_w = (const float*)d_in[7];
  const float* proj_b = (const float*)d_in[8];
  const float* n2g    = (const float*)d_in[9];
  const float* n2b    = (const float*)d_in[10];
  const float* fc1_w  = (const float*)d_in[11];
  const float* fc1_b  = (const float*)d_in[12];
  const float* fc2_w  = (const float*)d_in[13];
  const float* fc2_b  = (const float*)d_in[14];
  float* outp = (float*)d_out;
  (void)in_sizes; (void)n_in; (void)out_size; (void)ws_size; (void)mask;

  const size_t M = 200704;
  char* ws = (char*)d_ws;
  unsigned short* x2     = (unsigned short*)ws;              // 38.5 MB
  size_t o = M * 96 * 2;
  unsigned short* w1bf   = (unsigned short*)(ws + o); o += 384 * 96 * 2;
  unsigned short* w2bf   = (unsigned short*)(ws + o); o += 96 * 384 * 2;
  unsigned short* wqkvbf = (unsigned short*)(ws + o); o += 288 * 96 * 2;
  unsigned short* wprojbf= (unsigned short*)(ws + o); o += 96 * 96 * 2;
  float*          bqs    = (float*)(ws + o);          o += 288 * 4 + 64;
  float*          cbuf   = (float*)(ws + o); o += (size_t)4 * 3 * 4096 * 4;  // 196 KB

  cvt_all_kernel<<<434, 256, 0, stream>>>(
      fc1_w, w1bf, fc2_w, w2bf, qkv_w, wqkvbf, proj_w, wprojbf, qkv_b, bqs);
  cb_kernel<<<192, 256, 0, stream>>>(relt, mask, cbuf);
  fused_win_kernel<<<4096, 256, 0, stream>>>(
      x, n1g, n1b, wqkvbf, bqs, cbuf, wprojbf, proj_b, x2);
  mlp_mfma_kernel<<<3136, 384, 0, stream>>>(
      x2, n2g, n2b, w1bf, fc1_b, w2bf, fc2_b, outp);
}